// Round 2
// baseline (614.907 us; speedup 1.0000x reference)
//
#include <hip/hip_runtime.h>
#include <hip/hip_fp16.h>
#include <hip/hip_cooperative_groups.h>
#include <stdint.h>

namespace cg = cooperative_groups;

// GCN: x[N,8] -> GCNConv(8,64)+ReLU -> GCNConv(64,12)+ReLU -> segment_max(G) -> @Wl+bl -> log_softmax
// N=200000, E=1600000, G=2000. fp32 params; indices int32.
//
// R15: dispatch-count attack. R14's three in-kernel changes were all NEUTRAL
// (175.7 vs 176.1) while the kernels' combined roofline arithmetic is ~40us
// -> the ~135us gap must be inter-dispatch cost (graph gaps, drains, 782-block
// quantization tails, launch fixed costs), not in-kernel work. This round
// fuses the pipeline into TWO cooperative kernels with grid.sync():
//   k_csr = binA ; grid.sync ; binB
//   k_net = agg1f ; grid.sync ; agg2 ; grid.sync ; head   (k_head deleted)
// Dispatches per iteration: 7 -> 3 (memset + 2 coop). Grid sized by host
// occupancy query (cached); grid-stride loops keep any grid size correct.
// Also diagnostic: the fused kernels are big enough to show in top-5 counters.
// Algebra (R3): xd=x*dis ; z[t]=dis[t]*(xd[t]+sum xd[src]) ;
// y2=(relu(z@W1+b1)@W2)*dis ; h2[t]=relu(dis[t]*(y2[t]+sum y2[src])+b2) ;
// pool-max per graph ; head.

constexpr int IN_DIM = 8;
constexpr int H1 = 64;
constexpr int H2 = 12;
constexpr int NPB = 256;      // nodes per bucket (bucket = dst >> 8)
constexpr int NBK = 782;      // ceil(200000 / 256)
constexpr int CAP = 2560;     // per-bucket capacity (avg 2048, sd ~45 -> 11 sigma)
constexpr int CHUNK = 2048;   // edges per binA chunk
constexpr int SLOTS = 16;     // padded csr slots per node

__device__ __forceinline__ void acc_row8(float* acc, int4 rv) {
    const __half2* h = (const __half2*)&rv;
#pragma unroll
    for (int q = 0; q < 4; ++q) {
        float2 f = __half22float2(h[q]);
        acc[2 * q] += f.x; acc[2 * q + 1] += f.y;
    }
}

// ---------------- fused CSR build: binA chunks ; grid.sync ; binB buckets ----------
__global__ void __launch_bounds__(256) k_csr(
        const int* __restrict__ src, const int* __restrict__ dst,
        uint32_t* __restrict__ pairs, int* __restrict__ bcursor,
        const float* __restrict__ x, int* __restrict__ csr_pad,
        int* __restrict__ csr_ovf, unsigned int* __restrict__ meta,
        float* __restrict__ dis, __half2* __restrict__ xdh,
        int ne, int n) {
    __shared__ union {
        struct {                              // binA image: 22.7 KB
            int cnt[NBK]; int start[NBK]; int gb[NBK]; int tmp[256];
            uint32_t img[CHUNK]; uint16_t bkt[CHUNK];
        } A;
        struct {                              // binB image: 19 KB
            int hist[NPB]; int start[NPB]; int tmp[256]; int pad[NPB * SLOTS];
        } B;
    } S;
    int t = threadIdx.x;

    // ---------------- phase A: bucket-sorted staging -> run-coalesced pair writes ----
    const int nchunk = (ne + CHUNK - 1) / CHUNK;   // 782
    for (int c = blockIdx.x; c < nchunk; c += gridDim.x) {
        for (int i = t; i < NBK; i += 256) S.A.cnt[i] = 0;
        __syncthreads();
        int e0 = c * CHUNK;
        int cntblk = min(CHUNK, ne - e0);
        int rec[8];
#pragma unroll
        for (int i = 0; i < 8; ++i) {
            int e = e0 + i * 256 + t;
            rec[i] = -1;
            if (e < ne) {
                int d = __builtin_nontemporal_load(&dst[e]);
                int b = d >> 8;                                  // 10 bits
                int off = atomicAdd(&S.A.cnt[b], 1);             // 11 bits
                rec[i] = (off << 18) | ((d & 255) << 10) | b;    // 12|8|10
            }
        }
        __syncthreads();
        // exclusive scan of cnt[782] (pad to 1024), 4 elems/thread
        int b4 = t * 4;
        int v0 = (b4 < NBK) ? S.A.cnt[b4] : 0;
        int v1 = (b4 + 1 < NBK) ? S.A.cnt[b4 + 1] : 0;
        int v2 = (b4 + 2 < NBK) ? S.A.cnt[b4 + 2] : 0;
        int v3 = (b4 + 3 < NBK) ? S.A.cnt[b4 + 3] : 0;
        int p1 = v0, p2 = v0 + v1, p3 = v0 + v1 + v2, tot = p3 + v3;
        S.A.tmp[t] = tot;
        __syncthreads();
        for (int off = 1; off < 256; off <<= 1) {
            int u = (t >= off) ? S.A.tmp[t - off] : 0;
            __syncthreads();
            S.A.tmp[t] += u;
            __syncthreads();
        }
        int ex = S.A.tmp[t] - tot;
        if (b4 < NBK)     S.A.start[b4] = ex;
        if (b4 + 1 < NBK) S.A.start[b4 + 1] = ex + p1;
        if (b4 + 2 < NBK) S.A.start[b4 + 2] = ex + p2;
        if (b4 + 3 < NBK) S.A.start[b4 + 3] = ex + p3;
        // reserve global runs
        for (int b = t; b < NBK; b += 256) {
            int cb = S.A.cnt[b];
            S.A.gb[b] = (cb > 0) ? atomicAdd(&bcursor[b], cb) : 0;
        }
        __syncthreads();
        // place into sorted LDS image
#pragma unroll
        for (int i = 0; i < 8; ++i) {
            if (rec[i] < 0) continue;
            int e = e0 + i * 256 + t;
            int b = rec[i] & 1023;
            int dl = (rec[i] >> 10) & 255;
            int off = rec[i] >> 18;
            int pos = S.A.start[b] + off;
            S.A.img[pos] = ((uint32_t)dl << 18) |
                           (uint32_t)__builtin_nontemporal_load(&src[e]);
            S.A.bkt[pos] = (uint16_t)b;
        }
        __syncthreads();
        // run-coalesced flush
        for (int i = t; i < cntblk; i += 256) {
            int b = S.A.bkt[i];
            int goff = S.A.gb[b] + (i - S.A.start[b]);
            if (goff < CAP) pairs[(size_t)b * CAP + goff] = S.A.img[i];
        }
        __syncthreads();
    }

    __threadfence();
    cg::this_grid().sync();

    // ---------------- phase B: per-bucket counting sort -> padded csr + meta/dis/xdh --
    for (int b = blockIdx.x; b < NBK; b += gridDim.x) {
        int cnt = min(bcursor[b], CAP);
        const uint32_t* pb = pairs + (size_t)b * CAP;
        S.B.hist[t] = 0;
        for (int i = t; i < NPB * SLOTS; i += 256) S.B.pad[i] = n;   // dummy fill
        __syncthreads();
        // single atomic pass: histogram captures per-node arrival offset in regs
        uint32_t rdl[10];   // (off<<8) | dl ; sentinel 0xFFFFFFFF
        uint32_t rsx[10];   // src index
#pragma unroll
        for (int r = 0; r < 10; ++r) {
            int i = t + r * 256;
            rdl[r] = 0xFFFFFFFFu;
            if (i < cnt) {
                uint32_t p = __builtin_nontemporal_load(&pb[i]);
                int dl = (int)(p >> 18);
                int off = atomicAdd(&S.B.hist[dl], 1);
                rdl[r] = ((uint32_t)off << 8) | (uint32_t)dl;
                rsx[r] = p & 0x3FFFFu;
            }
        }
        __syncthreads();
        // exclusive scan of hist[256]
        int v = S.B.hist[t];
        S.B.tmp[t] = v;
        __syncthreads();
        for (int off = 1; off < 256; off <<= 1) {
            int u = (t >= off) ? S.B.tmp[t - off] : 0;
            __syncthreads();
            S.B.tmp[t] += u;
            __syncthreads();
        }
        S.B.start[t] = S.B.tmp[t] - v;
        __syncthreads();
        // meta + dis + xdh (1 node per thread, coalesced)
        int cb = b * CAP;
        int node = (b << 8) + t;
        if (node < n) {
            int deg = S.B.hist[t];
            meta[node] = ((unsigned int)deg << 21) | (unsigned int)(cb + S.B.start[t]);
            float di = rsqrtf((float)(deg + 1));   // +1 self-loop
            dis[node] = di;
            const float4* xi = (const float4*)(x + (size_t)node * IN_DIM);
            float4 a = xi[0], c2 = xi[1];
            union { __half2 h[4]; int iv[4]; } u;
            u.h[0] = __float22half2_rn(make_float2(a.x * di, a.y * di));
            u.h[1] = __float22half2_rn(make_float2(a.z * di, a.w * di));
            u.h[2] = __float22half2_rn(make_float2(c2.x * di, c2.y * di));
            u.h[3] = __float22half2_rn(make_float2(c2.z * di, c2.w * di));
            ((int4*)xdh)[node] = make_int4(u.iv[0], u.iv[1], u.iv[2], u.iv[3]);
        } else if (node == n) {
            ((int4*)xdh)[n] = make_int4(0, 0, 0, 0);           // dummy zero row
        }
        // place: first 16 per node into LDS pad; overflow -> bucket-strided csr_ovf
#pragma unroll
        for (int r = 0; r < 10; ++r) {
            if (rdl[r] == 0xFFFFFFFFu) continue;
            int dl = (int)(rdl[r] & 255u);
            int pos = (int)(rdl[r] >> 8);
            int sidx = (int)rsx[r];
            if (pos < SLOTS) S.B.pad[dl * SLOTS + pos] = sidx;
            else             csr_ovf[cb + S.B.start[dl] + pos] = sidx;
        }
        __syncthreads();
        // coalesced int4 flush (guard phantom nodes past n)
        for (int i = t; i < NPB * SLOTS / 4; i += 256) {
            int node2 = (b << 8) + (i >> 2);
            if (node2 < n)
                ((int4*)csr_pad)[(size_t)(b << 8) * 4 + i] = ((int4*)S.B.pad)[i];
        }
        __syncthreads();
    }
}

// ---------------- fused network: agg1+MLP ; grid.sync ; agg2+pool ; grid.sync ; head -
__global__ void __launch_bounds__(256) k_net(
        const int* __restrict__ csr_pad, const int* __restrict__ csr_ovf,
        const unsigned int* __restrict__ meta, const __half2* __restrict__ xdh,
        const float* __restrict__ dis, const float* __restrict__ W1,
        const float* __restrict__ b1, const float* __restrict__ W2,
        __half2* __restrict__ y2h, const float* __restrict__ b2,
        const int* __restrict__ batch, unsigned int* __restrict__ pooled,
        const float* __restrict__ Wl, const float* __restrict__ bl,
        float* __restrict__ out, int n, int g) {
    int t = threadIdx.x;
    int lane = t & 63;

    // ---------------- phase 1: agg1 + MLP (node per lane) --------------------------
    const int nt1 = (n + 1 + 255) / 256;
    for (int tile = blockIdx.x; tile < nt1; tile += gridDim.x) {
        int node = tile * 256 + t;
        if (node > n) continue;
        int4* orow = (int4*)y2h + (size_t)node * 2;
        if (node == n) {                     // dummy zero row for agg2
            orow[0] = make_int4(0, 0, 0, 0);
            orow[1] = make_int4(0, 0, 0, 0);
            continue;
        }
        const int4* pr = (const int4*)(csr_pad + (size_t)node * SLOTS);
        int4 p0 = pr[0], p1 = pr[1], p2 = pr[2], p3 = pr[3];
        unsigned int m = meta[node];
        const int4* xt = (const int4*)xdh;

        float acc[8] = {0, 0, 0, 0, 0, 0, 0, 0};
        int idx[16] = {p0.x, p0.y, p0.z, p0.w, p1.x, p1.y, p1.z, p1.w,
                       p2.x, p2.y, p2.z, p2.w, p3.x, p3.y, p3.z, p3.w};
        acc_row8(acc, xt[node]);             // self-loop
#pragma unroll
        for (int i = 0; i < 16; ++i) acc_row8(acc, xt[(size_t)idx[i]]);
        int deg = m >> 21;
        if (deg > SLOTS) {                   // rare overflow
            int r0 = (int)(m & 0x1FFFFF);
            for (int r = SLOTS; r < deg; ++r) acc_row8(acc, xt[(size_t)csr_ovf[r0 + r]]);
        }
        float di = dis[node];
        float z[8];
#pragma unroll
        for (int k = 0; k < 8; ++k) z[k] = acc[k] * di;

        float y2[H2];
#pragma unroll
        for (int j = 0; j < H2; ++j) y2[j] = 0.f;
        for (int d = 0; d < H1; ++d) {
            float h = b1[d];                              // uniform -> s_load
#pragma unroll
            for (int k = 0; k < 8; ++k) h = fmaf(z[k], W1[k * H1 + d], h);
            h = fmaxf(h, 0.f);
#pragma unroll
            for (int j = 0; j < H2; ++j) y2[j] = fmaf(h, W2[d * H2 + j], y2[j]);
        }
        union { __half2 h2v[8]; int iv[8]; } u;
#pragma unroll
        for (int q = 0; q < 6; ++q)
            u.h2v[q] = __float22half2_rn(make_float2(y2[2 * q] * di, y2[2 * q + 1] * di));
        u.h2v[6] = __float22half2_rn(make_float2(0.f, 0.f));
        u.h2v[7] = u.h2v[6];
        orow[0] = make_int4(u.iv[0], u.iv[1], u.iv[2], u.iv[3]);
        orow[1] = make_int4(u.iv[4], u.iv[5], u.iv[6], u.iv[7]);
    }

    __threadfence();
    cg::this_grid().sync();

    // ---------------- phase 2: agg2 + fused segmented max-pool ---------------------
    const int nt2 = (n + 255) / 256;
    for (int tile = blockIdx.x; tile < nt2; tile += gridDim.x) {
        int node = tile * 256 + t;
        bool active = node < n;
        float v[12] = {0, 0, 0, 0, 0, 0, 0, 0, 0, 0, 0, 0};
        int gid = 0x7fffffff;
        if (active) {
            const int4* pr = (const int4*)(csr_pad + (size_t)node * SLOTS);
            int4 p0 = pr[0], p1 = pr[1], p2 = pr[2], p3 = pr[3];
            unsigned int m = meta[node];
            const int4* yt = (const int4*)y2h;   // 32B rows = 2 int4
            float acc[12] = {0, 0, 0, 0, 0, 0, 0, 0, 0, 0, 0, 0};
            auto addrow = [&](int nb) {
                int4 ra = yt[(size_t)nb * 2];
                int4 rb = yt[(size_t)nb * 2 + 1];
                const __half2* ha = (const __half2*)&ra;
                const __half2* hb = (const __half2*)&rb;
#pragma unroll
                for (int q = 0; q < 4; ++q) {
                    float2 f = __half22float2(ha[q]);
                    acc[2 * q] += f.x; acc[2 * q + 1] += f.y;
                }
#pragma unroll
                for (int q = 0; q < 2; ++q) {
                    float2 f = __half22float2(hb[q]);
                    acc[8 + 2 * q] += f.x; acc[9 + 2 * q] += f.y;
                }
            };
            int idx[16] = {p0.x, p0.y, p0.z, p0.w, p1.x, p1.y, p1.z, p1.w,
                           p2.x, p2.y, p2.z, p2.w, p3.x, p3.y, p3.z, p3.w};
            addrow(node);                        // self-loop
#pragma unroll
            for (int i = 0; i < 16; ++i) addrow(idx[i]);
            int deg = m >> 21;
            if (deg > SLOTS) {                   // rare overflow
                int r0 = (int)(m & 0x1FFFFF);
                for (int r = SLOTS; r < deg; ++r) addrow(csr_ovf[r0 + r]);
            }
            float di = dis[node];
#pragma unroll
            for (int q = 0; q < 12; ++q) v[q] = fmaxf(fmaf(acc[q], di, b2[q]), 0.f);
            gid = batch[node];
        }
        // wave segmented inclusive max-scan (batch sorted => segments contiguous)
#pragma unroll
        for (int off = 1; off < 64; off <<= 1) {
            int g2 = __shfl_up(gid, off, 64);
            bool merge = (lane >= off) && (g2 == gid);
#pragma unroll
            for (int q = 0; q < 12; ++q) {
                float tv = __shfl_up(v[q], off, 64);
                if (merge) v[q] = fmaxf(v[q], tv);
            }
        }
        int gnext = __shfl_down(gid, 1, 64);
        bool last = (lane == 63) || (gnext != gid);
        if (last && gid != 0x7fffffff) {
            unsigned int* pp = pooled + (size_t)gid * 12;
#pragma unroll
            for (int q = 0; q < 12; ++q) atomicMax(&pp[q], __float_as_uint(v[q]));
        }
    }

    __threadfence();
    cg::this_grid().sync();

    // ---------------- phase 3: head (logits + log_softmax) -------------------------
    for (int i = blockIdx.x * 256 + t; i < g; i += gridDim.x * 256) {
        float l0 = bl[0], l1 = bl[1];
#pragma unroll
        for (int k = 0; k < H2; ++k) {
            float pv = __uint_as_float(pooled[(size_t)i * 12 + k]);
            l0 = fmaf(pv, Wl[k * 2 + 0], l0);
            l1 = fmaf(pv, Wl[k * 2 + 1], l1);
        }
        float m = fmaxf(l0, l1);
        float lse = m + logf(expf(l0 - m) + expf(l1 - m));
        out[i * 2 + 0] = l0 - lse;
        out[i * 2 + 1] = l1 - lse;
    }
}

extern "C" void kernel_launch(void* const* d_in, const int* in_sizes, int n_in,
                              void* d_out, int out_size, void* d_ws, size_t ws_size,
                              hipStream_t stream) {
    const float* x   = (const float*)d_in[0];
    const int* ei    = (const int*)d_in[1];
    const int* batch = (const int*)d_in[2];
    const float* W1  = (const float*)d_in[3];
    const float* b1  = (const float*)d_in[4];
    const float* W2  = (const float*)d_in[5];
    const float* b2  = (const float*)d_in[6];
    const float* Wl  = (const float*)d_in[7];
    const float* bl  = (const float*)d_in[8];
    float* out = (float*)d_out;

    const int N = in_sizes[0] / IN_DIM;   // 200000
    const int E = in_sizes[1] / 2;        // 1600000
    const int G = out_size / 2;           // 2000
    const int* src = ei;
    const int* dst = ei + E;

    // workspace carve, 64B-aligned (bcursor+pooled first: single zeroing memset)
    char* wp = (char*)d_ws;
    auto carve = [&](size_t bytes) {
        char* p = wp;
        wp += (bytes + 63) & ~(size_t)63;
        return p;
    };
    int*          bcursor = (int*)carve(NBK * 4);
    unsigned int* pooled  = (unsigned int*)carve((size_t)G * H2 * 4);
    unsigned int* meta    = (unsigned int*)carve((size_t)N * 4);
    float*        dis     = (float*)carve((size_t)N * 4);
    __half2*      xdh     = (__half2*)carve((size_t)(N + 1) * 16);   // 16B rows
    __half2*      y2h     = (__half2*)carve((size_t)(N + 1) * 32);   // 32B rows
    uint32_t*     pairs   = (uint32_t*)carve((size_t)NBK * CAP * 4);
    int*          csr_pad = (int*)carve((size_t)N * SLOTS * 4);
    int*          csr_ovf = (int*)carve((size_t)NBK * CAP * 4);

    size_t zspan = (char*)(pooled + (size_t)G * H2) - (char*)bcursor;
    (void)hipMemsetAsync(bcursor, 0, zspan, stream);

    // cooperative grid sizes from occupancy (cached; 256 CUs on MI355X)
    static int gA = 0, gB = 0;
    if (gA == 0) {
        int mbA = 1, mbB = 1;
        (void)hipOccupancyMaxActiveBlocksPerMultiprocessor(&mbA, k_csr, 256, 0);
        (void)hipOccupancyMaxActiveBlocksPerMultiprocessor(&mbB, k_net, 256, 0);
        if (mbA < 1) mbA = 1;
        if (mbB < 1) mbB = 1;
        long long ca = (long long)mbA * 256, cb = (long long)mbB * 256;
        gA = (int)(ca < NBK ? ca : NBK);
        gB = (int)(cb < NBK ? cb : NBK);
    }

    int E_ = E, N_ = N, G_ = G;
    const int* srcp = src; const int* dstp = dst;
    const float* xp = x;
    void* pa[] = {(void*)&srcp, (void*)&dstp, (void*)&pairs, (void*)&bcursor,
                  (void*)&xp, (void*)&csr_pad, (void*)&csr_ovf, (void*)&meta,
                  (void*)&dis, (void*)&xdh, (void*)&E_, (void*)&N_};
    (void)hipLaunchCooperativeKernel((const void*)k_csr, dim3(gA), dim3(256),
                                     pa, 0, stream);

    const float* W1p = W1; const float* b1p = b1; const float* W2p = W2;
    const float* b2p = b2; const int* batchp = batch;
    const float* Wlp = Wl; const float* blp = bl; float* outp = out;
    void* pb[] = {(void*)&csr_pad, (void*)&csr_ovf, (void*)&meta, (void*)&xdh,
                  (void*)&dis, (void*)&W1p, (void*)&b1p, (void*)&W2p, (void*)&y2h,
                  (void*)&b2p, (void*)&batchp, (void*)&pooled, (void*)&Wlp,
                  (void*)&blp, (void*)&outp, (void*)&N_, (void*)&G_};
    (void)hipLaunchCooperativeKernel((const void*)k_net, dim3(gB), dim3(256),
                                     pb, 0, stream);
}

// Round 3
// 259.627 us; speedup vs baseline: 2.3684x; 2.3684x over previous
//
#include <hip/hip_runtime.h>
#include <hip/hip_fp16.h>
#include <stdint.h>

// GCN: x[N,8] -> GCNConv(8,64)+ReLU -> GCNConv(64,12)+ReLU -> segment_max(G) -> @Wl+bl -> log_softmax
// N=200000, E=1600000, G=2000. fp32 params; indices int32.
//
// R16: revert R15's cooperative fusion (4-6x uniform slowdown on coop dispatch;
// k_net counters showed VALUBusy 3%, HBM 3.5% -- pure stall). Back to the R14
// 5-kernel pipeline, plus the lever R15's counters exposed: agg kernels ran at
// 12.2 waves/CU (work-limited: 1 node/thread) while latency-bound on random
// gathers (y2h 6.4MB > 4MB per-XCD L2). This round: 2 LANES PER NODE in
// k_agg1f and k_agg2 -> 400K threads, 24.4 waves/CU, 2x outstanding misses,
// half the per-thread dependency chain. Pair combines via __shfl_xor(.,1,64).
// agg1f also splits the 64-step MLP across the pair (d=0..31 / 32..63).
// Algebra (R3): xd=x*dis ; z[t]=dis[t]*(xd[t]+sum xd[src]) ;
// y2=(relu(z@W1+b1)@W2)*dis ; h2[t]=relu(dis[t]*(y2[t]+sum y2[src])+b2) ;
// pool-max per graph ; head.

constexpr int IN_DIM = 8;
constexpr int H1 = 64;
constexpr int H2 = 12;
constexpr int NPB = 256;      // nodes per bucket (bucket = dst >> 8)
constexpr int NBK = 782;      // ceil(200000 / 256)
constexpr int CAP = 2560;     // per-bucket capacity (avg 2048, sd ~45 -> 11 sigma)
constexpr int CHUNK = 2048;   // edges per binA block
constexpr int SLOTS = 16;     // padded csr slots per node

__device__ __forceinline__ void acc_row8(float* acc, int4 rv) {
    const __half2* h = (const __half2*)&rv;
#pragma unroll
    for (int q = 0; q < 4; ++q) {
        float2 f = __half22float2(h[q]);
        acc[2 * q] += f.x; acc[2 * q + 1] += f.y;
    }
}

// ---------------- pass A: bucket-sorted staging -> run-coalesced pair writes ----------
__global__ void __launch_bounds__(256) k_binA(
        const int* __restrict__ src, const int* __restrict__ dst,
        uint32_t* __restrict__ pairs, int* __restrict__ bcursor, int ne) {
    __shared__ int s_cnt[NBK];        // per-bucket count
    __shared__ int s_start[NBK];      // block-local exclusive starts
    __shared__ int s_gb[NBK];         // global run base
    __shared__ int s_tmp[256];
    __shared__ uint32_t s_img[CHUNK]; // bucket-sorted pairs (8 KB)
    __shared__ uint16_t s_bkt[CHUNK]; // bucket id per slot (4 KB)
    int t = threadIdx.x;
    for (int i = t; i < NBK; i += 256) s_cnt[i] = 0;
    __syncthreads();
    int e0 = blockIdx.x * CHUNK;
    int cntblk = min(CHUNK, ne - e0);
    int rec[8];
#pragma unroll
    for (int i = 0; i < 8; ++i) {
        int e = e0 + i * 256 + t;
        rec[i] = -1;
        if (e < ne) {
            int d = __builtin_nontemporal_load(&dst[e]);
            int b = d >> 8;                                  // 10 bits
            int off = atomicAdd(&s_cnt[b], 1);               // 11 bits
            rec[i] = (off << 18) | ((d & 255) << 10) | b;    // 12|8|10
        }
    }
    __syncthreads();
    // exclusive scan of s_cnt[782] (pad to 1024), 4 elems/thread
    int b4 = t * 4;
    int v0 = (b4 < NBK) ? s_cnt[b4] : 0;
    int v1 = (b4 + 1 < NBK) ? s_cnt[b4 + 1] : 0;
    int v2 = (b4 + 2 < NBK) ? s_cnt[b4 + 2] : 0;
    int v3 = (b4 + 3 < NBK) ? s_cnt[b4 + 3] : 0;
    int p1 = v0, p2 = v0 + v1, p3 = v0 + v1 + v2, tot = p3 + v3;
    s_tmp[t] = tot;
    __syncthreads();
    for (int off = 1; off < 256; off <<= 1) {
        int u = (t >= off) ? s_tmp[t - off] : 0;
        __syncthreads();
        s_tmp[t] += u;
        __syncthreads();
    }
    int ex = s_tmp[t] - tot;
    if (b4 < NBK)     s_start[b4] = ex;
    if (b4 + 1 < NBK) s_start[b4 + 1] = ex + p1;
    if (b4 + 2 < NBK) s_start[b4 + 2] = ex + p2;
    if (b4 + 3 < NBK) s_start[b4 + 3] = ex + p3;
    // reserve global runs
    for (int b = t; b < NBK; b += 256) {
        int c = s_cnt[b];
        s_gb[b] = (c > 0) ? atomicAdd(&bcursor[b], c) : 0;
    }
    __syncthreads();
    // place into sorted LDS image
#pragma unroll
    for (int i = 0; i < 8; ++i) {
        if (rec[i] < 0) continue;
        int e = e0 + i * 256 + t;
        int b = rec[i] & 1023;
        int dl = (rec[i] >> 10) & 255;
        int off = rec[i] >> 18;
        int pos = s_start[b] + off;
        s_img[pos] = ((uint32_t)dl << 18) | (uint32_t)__builtin_nontemporal_load(&src[e]);
        s_bkt[pos] = (uint16_t)b;
    }
    __syncthreads();
    // run-coalesced flush (consecutive i in a bucket -> consecutive global addrs)
    for (int i = t; i < cntblk; i += 256) {
        int b = s_bkt[i];
        int goff = s_gb[b] + (i - s_start[b]);
        if (goff < CAP) pairs[(size_t)b * CAP + goff] = s_img[i];
    }
}

// ---------------- pass B: per-bucket counting sort -> PADDED csr + meta/dis/xdh ----------
__global__ void __launch_bounds__(256) k_binB(
        const uint32_t* __restrict__ pairs, const int* __restrict__ bcursor,
        const float* __restrict__ x, int* __restrict__ csr_pad,
        int* __restrict__ csr_ovf, unsigned int* __restrict__ meta,
        float* __restrict__ dis, __half2* __restrict__ xdh, int n) {
    __shared__ int s_hist[NPB];
    __shared__ int s_start[NPB];
    __shared__ int s_tmp[256];
    __shared__ int s_pad[NPB * SLOTS];   // 16 KB padded image
    int b = blockIdx.x;
    int t = threadIdx.x;
    int cnt = min(bcursor[b], CAP);
    const uint32_t* pb = pairs + (size_t)b * CAP;
    s_hist[t] = 0;
    for (int i = t; i < NPB * SLOTS; i += 256) s_pad[i] = n;   // dummy fill
    __syncthreads();
    // single atomic pass -- histogram captures per-node arrival offset in regs
    uint32_t rdl[10];   // (off<<8) | dl ; sentinel 0xFFFFFFFF
    uint32_t rsx[10];   // src index
#pragma unroll
    for (int r = 0; r < 10; ++r) {
        int i = t + r * 256;
        rdl[r] = 0xFFFFFFFFu;
        if (i < cnt) {
            uint32_t p = __builtin_nontemporal_load(&pb[i]);
            int dl = (int)(p >> 18);
            int off = atomicAdd(&s_hist[dl], 1);
            rdl[r] = ((uint32_t)off << 8) | (uint32_t)dl;
            rsx[r] = p & 0x3FFFFu;
        }
    }
    __syncthreads();
    // exclusive scan of s_hist[256]
    int v = s_hist[t];
    s_tmp[t] = v;
    __syncthreads();
    for (int off = 1; off < 256; off <<= 1) {
        int u = (t >= off) ? s_tmp[t - off] : 0;
        __syncthreads();
        s_tmp[t] += u;
        __syncthreads();
    }
    s_start[t] = s_tmp[t] - v;
    __syncthreads();
    // meta + dis + xdh (1 node per thread, coalesced)
    int cb = b * CAP;                    // bucket-strided overflow base
    int node = (b << 8) + t;
    if (node < n) {
        int deg = s_hist[t];
        meta[node] = ((unsigned int)deg << 21) | (unsigned int)(cb + s_start[t]);
        float di = rsqrtf((float)(deg + 1));   // +1 self-loop
        dis[node] = di;
        const float4* xi = (const float4*)(x + (size_t)node * IN_DIM);
        float4 a = xi[0], c = xi[1];
        union { __half2 h[4]; int iv[4]; } u;
        u.h[0] = __float22half2_rn(make_float2(a.x * di, a.y * di));
        u.h[1] = __float22half2_rn(make_float2(a.z * di, a.w * di));
        u.h[2] = __float22half2_rn(make_float2(c.x * di, c.y * di));
        u.h[3] = __float22half2_rn(make_float2(c.z * di, c.w * di));
        ((int4*)xdh)[node] = make_int4(u.iv[0], u.iv[1], u.iv[2], u.iv[3]);
    } else if (node == n) {
        ((int4*)xdh)[n] = make_int4(0, 0, 0, 0);           // dummy zero row
    }
    // place: first 16 per node into LDS pad; overflow -> bucket-strided csr_ovf (rare)
#pragma unroll
    for (int r = 0; r < 10; ++r) {
        if (rdl[r] == 0xFFFFFFFFu) continue;
        int dl = (int)(rdl[r] & 255u);
        int pos = (int)(rdl[r] >> 8);
        int sidx = (int)rsx[r];
        if (pos < SLOTS) s_pad[dl * SLOTS + pos] = sidx;
        else             csr_ovf[cb + s_start[dl] + pos] = sidx;
    }
    __syncthreads();
    // coalesced int4 flush (guard phantom nodes past n)
    for (int i = t; i < NPB * SLOTS / 4; i += 256) {
        int node2 = (b << 8) + (i >> 2);
        if (node2 < n)
            ((int4*)csr_pad)[(size_t)(b << 8) * 4 + i] = ((int4*)s_pad)[i];
    }
}

// ---------------- agg1 + MLP fused: node per LANE-PAIR (R16) ----------------
// lane a: gathers self + idx[0..7]; lane b: idx[8..15] + overflow.
// pair combines z via shfl_xor; MLP split d=0..31 / d=32..63; y2 combined;
// pair splits the two 16B output stores.
__global__ void __launch_bounds__(256) k_agg1f(
        const int* __restrict__ csr_pad, const int* __restrict__ csr_ovf,
        const unsigned int* __restrict__ meta, const __half2* __restrict__ xdh,
        const float* __restrict__ dis, const float* __restrict__ W1,
        const float* __restrict__ b1, const float* __restrict__ W2,
        __half2* __restrict__ y2h, int n) {
    int gtid = blockIdx.x * 256 + threadIdx.x;
    int node = gtid >> 1;
    int pl = gtid & 1;                   // pair lane
    if (node > n) return;
    int4* orow = (int4*)y2h + (size_t)node * 2;
    if (node == n) {                     // dummy zero row for agg2
        orow[pl] = make_int4(0, 0, 0, 0);
        return;
    }
    // each pair-lane reads its 32B half of the csr row (fully coalesced)
    const int4* pr = (const int4*)(csr_pad + (size_t)node * SLOTS) + pl * 2;
    int4 p0 = pr[0], p1 = pr[1];
    unsigned int m = meta[node];
    const int4* xt = (const int4*)xdh;

    float acc[8] = {0, 0, 0, 0, 0, 0, 0, 0};
    int idx[8] = {p0.x, p0.y, p0.z, p0.w, p1.x, p1.y, p1.z, p1.w};
    if (pl == 0) acc_row8(acc, xt[node]);            // self-loop on lane a
#pragma unroll
    for (int i = 0; i < 8; ++i) acc_row8(acc, xt[(size_t)idx[i]]);
    int deg = m >> 21;
    if (deg > SLOTS && pl == 1) {                    // rare overflow -> lane b
        int r0 = (int)(m & 0x1FFFFF);
        for (int r = SLOTS; r < deg; ++r) acc_row8(acc, xt[(size_t)csr_ovf[r0 + r]]);
    }
    // pair-combine aggregate (both lanes end with full z)
    float di = dis[node];
    float z[8];
#pragma unroll
    for (int k = 0; k < 8; ++k) {
        float a2 = acc[k] + __shfl_xor(acc[k], 1, 64);
        z[k] = a2 * di;
    }
    // MLP: pair splits the 64 hidden units
    float y2[H2];
#pragma unroll
    for (int j = 0; j < H2; ++j) y2[j] = 0.f;
    int d0 = pl * 32;
    for (int d = d0; d < d0 + 32; ++d) {
        float h = b1[d];                              // uniform -> s_load
#pragma unroll
        for (int k = 0; k < 8; ++k) h = fmaf(z[k], W1[k * H1 + d], h);
        h = fmaxf(h, 0.f);
#pragma unroll
        for (int j = 0; j < H2; ++j) y2[j] = fmaf(h, W2[d * H2 + j], y2[j]);
    }
    // pair-combine y2 (both lanes end with full y2)
#pragma unroll
    for (int j = 0; j < H2; ++j) y2[j] += __shfl_xor(y2[j], 1, 64);
    union { __half2 h2v[8]; int iv[8]; } u;
#pragma unroll
    for (int q = 0; q < 6; ++q)
        u.h2v[q] = __float22half2_rn(make_float2(y2[2 * q] * di, y2[2 * q + 1] * di));
    u.h2v[6] = __float22half2_rn(make_float2(0.f, 0.f));
    u.h2v[7] = u.h2v[6];
    // pair splits the two 16B stores
    if (pl == 0) orow[0] = make_int4(u.iv[0], u.iv[1], u.iv[2], u.iv[3]);
    else         orow[1] = make_int4(u.iv[4], u.iv[5], u.iv[6], u.iv[7]);
}

// ---------------- layer-2 aggregation + FUSED segmented max-pool ----------------
// node per LANE-PAIR (R16): lane a gathers self + idx[0..7], lane b idx[8..15]
// + overflow; pair-adds acc via shfl_xor; both lanes hold full h2, so the
// existing 64-wide segmented max-scan works unchanged (gid duplicated per pair
// merges benignly; write-guard still fires once per segment boundary).
__global__ void __launch_bounds__(256) k_agg2(
        const int* __restrict__ csr_pad, const int* __restrict__ csr_ovf,
        const unsigned int* __restrict__ meta, const __half2* __restrict__ y2h,
        const float* __restrict__ dis, const float* __restrict__ b2,
        const int* __restrict__ batch, unsigned int* __restrict__ pooled, int n) {
    int gtid = blockIdx.x * 256 + threadIdx.x;
    int node = gtid >> 1;
    int pl = gtid & 1;
    int lane = threadIdx.x & 63;
    bool active = node < n;
    float v[12] = {0, 0, 0, 0, 0, 0, 0, 0, 0, 0, 0, 0};
    int gid = 0x7fffffff;
    if (active) {
        const int4* pr = (const int4*)(csr_pad + (size_t)node * SLOTS) + pl * 2;
        int4 p0 = pr[0], p1 = pr[1];
        unsigned int m = meta[node];
        const int4* yt = (const int4*)y2h;   // 32B rows = 2 int4
        float acc[12] = {0, 0, 0, 0, 0, 0, 0, 0, 0, 0, 0, 0};
        auto addrow = [&](int nb) {
            int4 ra = yt[(size_t)nb * 2];
            int4 rb = yt[(size_t)nb * 2 + 1];
            const __half2* ha = (const __half2*)&ra;
            const __half2* hb = (const __half2*)&rb;
#pragma unroll
            for (int q = 0; q < 4; ++q) {
                float2 f = __half22float2(ha[q]);
                acc[2 * q] += f.x; acc[2 * q + 1] += f.y;
            }
#pragma unroll
            for (int q = 0; q < 2; ++q) {
                float2 f = __half22float2(hb[q]);
                acc[8 + 2 * q] += f.x; acc[9 + 2 * q] += f.y;
            }
        };
        int idx[8] = {p0.x, p0.y, p0.z, p0.w, p1.x, p1.y, p1.z, p1.w};
        if (pl == 0) addrow(node);           // self-loop on lane a
#pragma unroll
        for (int i = 0; i < 8; ++i) addrow(idx[i]);
        int deg = m >> 21;
        if (deg > SLOTS && pl == 1) {        // rare overflow -> lane b
            int r0 = (int)(m & 0x1FFFFF);
            for (int r = SLOTS; r < deg; ++r) addrow(csr_ovf[r0 + r]);
        }
        float di = dis[node];
#pragma unroll
        for (int q = 0; q < 12; ++q) {
            float a2 = acc[q] + __shfl_xor(acc[q], 1, 64);   // pair-combine
            v[q] = fmaxf(fmaf(a2, di, b2[q]), 0.f);
        }
        gid = batch[node];
    }
    // wave segmented inclusive max-scan (batch sorted => segments contiguous)
#pragma unroll
    for (int off = 1; off < 64; off <<= 1) {
        int g2 = __shfl_up(gid, off, 64);
        bool merge = (lane >= off) && (g2 == gid);
#pragma unroll
        for (int q = 0; q < 12; ++q) {
            float tv = __shfl_up(v[q], off, 64);
            if (merge) v[q] = fmaxf(v[q], tv);
        }
    }
    int gnext = __shfl_down(gid, 1, 64);
    bool last = (lane == 63) || (gnext != gid);
    if (last && gid != 0x7fffffff) {
        unsigned int* pp = pooled + (size_t)gid * 12;
#pragma unroll
        for (int q = 0; q < 12; ++q) atomicMax(&pp[q], __float_as_uint(v[q]));
    }
}

// ---------------- head: logits + log_softmax from pooled ----------------
__global__ void k_head(const unsigned int* __restrict__ pooled,
                       const float* __restrict__ Wl, const float* __restrict__ bl,
                       float* __restrict__ out, int g) {
    int i = blockIdx.x * 256 + threadIdx.x;
    if (i >= g) return;
    float l0 = bl[0], l1 = bl[1];
#pragma unroll
    for (int k = 0; k < H2; ++k) {
        float pv = __uint_as_float(pooled[(size_t)i * 12 + k]);
        l0 = fmaf(pv, Wl[k * 2 + 0], l0);
        l1 = fmaf(pv, Wl[k * 2 + 1], l1);
    }
    float m = fmaxf(l0, l1);
    float lse = m + logf(expf(l0 - m) + expf(l1 - m));
    out[i * 2 + 0] = l0 - lse;
    out[i * 2 + 1] = l1 - lse;
}

extern "C" void kernel_launch(void* const* d_in, const int* in_sizes, int n_in,
                              void* d_out, int out_size, void* d_ws, size_t ws_size,
                              hipStream_t stream) {
    const float* x   = (const float*)d_in[0];
    const int* ei    = (const int*)d_in[1];
    const int* batch = (const int*)d_in[2];
    const float* W1  = (const float*)d_in[3];
    const float* b1  = (const float*)d_in[4];
    const float* W2  = (const float*)d_in[5];
    const float* b2  = (const float*)d_in[6];
    const float* Wl  = (const float*)d_in[7];
    const float* bl  = (const float*)d_in[8];
    float* out = (float*)d_out;

    const int N = in_sizes[0] / IN_DIM;   // 200000
    const int E = in_sizes[1] / 2;        // 1600000
    const int G = out_size / 2;           // 2000
    const int* src = ei;
    const int* dst = ei + E;

    auto cdiv = [](long long a, int b) { return (int)((a + b - 1) / b); };

    // workspace carve, 64B-aligned (bcursor+pooled first: single zeroing memset)
    char* wp = (char*)d_ws;
    auto carve = [&](size_t bytes) {
        char* p = wp;
        wp += (bytes + 63) & ~(size_t)63;
        return p;
    };
    int*          bcursor = (int*)carve(NBK * 4);
    unsigned int* pooled  = (unsigned int*)carve((size_t)G * H2 * 4);
    unsigned int* meta    = (unsigned int*)carve((size_t)N * 4);
    float*        dis     = (float*)carve((size_t)N * 4);
    __half2*      xdh     = (__half2*)carve((size_t)(N + 1) * 16);   // 16B rows
    __half2*      y2h     = (__half2*)carve((size_t)(N + 1) * 32);   // 32B rows
    uint32_t*     pairs   = (uint32_t*)carve((size_t)NBK * CAP * 4);
    int*          csr_pad = (int*)carve((size_t)N * SLOTS * 4);
    int*          csr_ovf = (int*)carve((size_t)NBK * CAP * 4);

    size_t zspan = (char*)(pooled + (size_t)G * H2) - (char*)bcursor;
    (void)hipMemsetAsync(bcursor, 0, zspan, stream);

    // CSR build (bucket-sorted binA -> padded csr in binB, fused meta/dis/xdh)
    k_binA<<<cdiv(E, CHUNK), 256, 0, stream>>>(src, dst, pairs, bcursor, E);
    k_binB<<<NBK, 256, 0, stream>>>(pairs, bcursor, x, csr_pad, csr_ovf,
                                    meta, dis, xdh, N);

    // fused layer-1 agg + MLP (2 lanes/node), layer-2 agg + fused pool (2 lanes/node)
    k_agg1f<<<cdiv(2LL * (N + 1), 256), 256, 0, stream>>>(
        csr_pad, csr_ovf, meta, xdh, dis, W1, b1, W2, y2h, N);
    k_agg2<<<cdiv(2LL * N, 256), 256, 0, stream>>>(csr_pad, csr_ovf, meta, y2h,
                                                   dis, b2, batch, pooled, N);
    k_head<<<cdiv(G, 256), 256, 0, stream>>>(pooled, Wl, bl, out, G);
}

// Round 4
// 182.162 us; speedup vs baseline: 3.3756x; 1.4253x over previous
//
#include <hip/hip_runtime.h>
#include <hip/hip_fp16.h>
#include <stdint.h>

// GCN: x[N,8] -> GCNConv(8,64)+ReLU -> GCNConv(64,12)+ReLU -> segment_max(G) -> @Wl+bl -> log_softmax
// N=200000, E=1600000, G=2000. fp32 params; indices int32.
//
// R17: revert R16's pair-split (it made the MLP weight index lane-dependent ->
// killed s_load scalarization -> ~670 VMEM loads/thread -> agg1f 105us).
// Back to R14's 1-lane/node agg kernels (weights wave-uniform -> scalar pipe).
// New lever from R16's counters: agg1f's xdh table (3.2MB) is L2-resident
// (FETCH=20MB = streams only), but agg2's y2h (6.4MB) is NOT (>4MB per-XCD L2)
// -> ~100MB of 64B-line HBM fetch on random 32B gathers + ~900cy miss latency.
// Fix: channel-split y2 into y2a (ch0-7, int4/node, 3.2MB) + y2b (ch8-11,
// int2/node, 1.6MB); agg2 becomes TWO passes, each gathering an L2-resident
// table. Extra cost: one dispatch + ~15MB re-streamed csr/meta -> ~3us.
// Algebra (R3): xd=x*dis ; z[t]=dis[t]*(xd[t]+sum xd[src]) ;
// y2=(relu(z@W1+b1)@W2)*dis ; h2[t]=relu(dis[t]*(y2[t]+sum y2[src])+b2) ;
// pool-max per graph ; head.

constexpr int IN_DIM = 8;
constexpr int H1 = 64;
constexpr int H2 = 12;
constexpr int NPB = 256;      // nodes per bucket (bucket = dst >> 8)
constexpr int NBK = 782;      // ceil(200000 / 256)
constexpr int CAP = 2560;     // per-bucket capacity (avg 2048, sd ~45 -> 11 sigma)
constexpr int CHUNK = 2048;   // edges per binA block
constexpr int SLOTS = 16;     // padded csr slots per node

__device__ __forceinline__ void acc_row8(float* acc, int4 rv) {
    const __half2* h = (const __half2*)&rv;
#pragma unroll
    for (int q = 0; q < 4; ++q) {
        float2 f = __half22float2(h[q]);
        acc[2 * q] += f.x; acc[2 * q + 1] += f.y;
    }
}

// ---------------- pass A: bucket-sorted staging -> run-coalesced pair writes ----------
__global__ void __launch_bounds__(256) k_binA(
        const int* __restrict__ src, const int* __restrict__ dst,
        uint32_t* __restrict__ pairs, int* __restrict__ bcursor, int ne) {
    __shared__ int s_cnt[NBK];        // per-bucket count
    __shared__ int s_start[NBK];      // block-local exclusive starts
    __shared__ int s_gb[NBK];         // global run base
    __shared__ int s_tmp[256];
    __shared__ uint32_t s_img[CHUNK]; // bucket-sorted pairs (8 KB)
    __shared__ uint16_t s_bkt[CHUNK]; // bucket id per slot (4 KB)
    int t = threadIdx.x;
    for (int i = t; i < NBK; i += 256) s_cnt[i] = 0;
    __syncthreads();
    int e0 = blockIdx.x * CHUNK;
    int cntblk = min(CHUNK, ne - e0);
    int rec[8];
#pragma unroll
    for (int i = 0; i < 8; ++i) {
        int e = e0 + i * 256 + t;
        rec[i] = -1;
        if (e < ne) {
            int d = __builtin_nontemporal_load(&dst[e]);
            int b = d >> 8;                                  // 10 bits
            int off = atomicAdd(&s_cnt[b], 1);               // 11 bits
            rec[i] = (off << 18) | ((d & 255) << 10) | b;    // 12|8|10
        }
    }
    __syncthreads();
    // exclusive scan of s_cnt[782] (pad to 1024), 4 elems/thread
    int b4 = t * 4;
    int v0 = (b4 < NBK) ? s_cnt[b4] : 0;
    int v1 = (b4 + 1 < NBK) ? s_cnt[b4 + 1] : 0;
    int v2 = (b4 + 2 < NBK) ? s_cnt[b4 + 2] : 0;
    int v3 = (b4 + 3 < NBK) ? s_cnt[b4 + 3] : 0;
    int p1 = v0, p2 = v0 + v1, p3 = v0 + v1 + v2, tot = p3 + v3;
    s_tmp[t] = tot;
    __syncthreads();
    for (int off = 1; off < 256; off <<= 1) {
        int u = (t >= off) ? s_tmp[t - off] : 0;
        __syncthreads();
        s_tmp[t] += u;
        __syncthreads();
    }
    int ex = s_tmp[t] - tot;
    if (b4 < NBK)     s_start[b4] = ex;
    if (b4 + 1 < NBK) s_start[b4 + 1] = ex + p1;
    if (b4 + 2 < NBK) s_start[b4 + 2] = ex + p2;
    if (b4 + 3 < NBK) s_start[b4 + 3] = ex + p3;
    // reserve global runs
    for (int b = t; b < NBK; b += 256) {
        int c = s_cnt[b];
        s_gb[b] = (c > 0) ? atomicAdd(&bcursor[b], c) : 0;
    }
    __syncthreads();
    // place into sorted LDS image
#pragma unroll
    for (int i = 0; i < 8; ++i) {
        if (rec[i] < 0) continue;
        int e = e0 + i * 256 + t;
        int b = rec[i] & 1023;
        int dl = (rec[i] >> 10) & 255;
        int off = rec[i] >> 18;
        int pos = s_start[b] + off;
        s_img[pos] = ((uint32_t)dl << 18) | (uint32_t)__builtin_nontemporal_load(&src[e]);
        s_bkt[pos] = (uint16_t)b;
    }
    __syncthreads();
    // run-coalesced flush (consecutive i in a bucket -> consecutive global addrs)
    for (int i = t; i < cntblk; i += 256) {
        int b = s_bkt[i];
        int goff = s_gb[b] + (i - s_start[b]);
        if (goff < CAP) pairs[(size_t)b * CAP + goff] = s_img[i];
    }
}

// ---------------- pass B: per-bucket counting sort -> PADDED csr + meta/dis/xdh ----------
__global__ void __launch_bounds__(256) k_binB(
        const uint32_t* __restrict__ pairs, const int* __restrict__ bcursor,
        const float* __restrict__ x, int* __restrict__ csr_pad,
        int* __restrict__ csr_ovf, unsigned int* __restrict__ meta,
        float* __restrict__ dis, __half2* __restrict__ xdh, int n) {
    __shared__ int s_hist[NPB];
    __shared__ int s_start[NPB];
    __shared__ int s_tmp[256];
    __shared__ int s_pad[NPB * SLOTS];   // 16 KB padded image
    int b = blockIdx.x;
    int t = threadIdx.x;
    int cnt = min(bcursor[b], CAP);
    const uint32_t* pb = pairs + (size_t)b * CAP;
    s_hist[t] = 0;
    for (int i = t; i < NPB * SLOTS; i += 256) s_pad[i] = n;   // dummy fill
    __syncthreads();
    // single atomic pass -- histogram captures per-node arrival offset in regs
    uint32_t rdl[10];   // (off<<8) | dl ; sentinel 0xFFFFFFFF
    uint32_t rsx[10];   // src index
#pragma unroll
    for (int r = 0; r < 10; ++r) {
        int i = t + r * 256;
        rdl[r] = 0xFFFFFFFFu;
        if (i < cnt) {
            uint32_t p = __builtin_nontemporal_load(&pb[i]);
            int dl = (int)(p >> 18);
            int off = atomicAdd(&s_hist[dl], 1);
            rdl[r] = ((uint32_t)off << 8) | (uint32_t)dl;
            rsx[r] = p & 0x3FFFFu;
        }
    }
    __syncthreads();
    // exclusive scan of s_hist[256]
    int v = s_hist[t];
    s_tmp[t] = v;
    __syncthreads();
    for (int off = 1; off < 256; off <<= 1) {
        int u = (t >= off) ? s_tmp[t - off] : 0;
        __syncthreads();
        s_tmp[t] += u;
        __syncthreads();
    }
    s_start[t] = s_tmp[t] - v;
    __syncthreads();
    // meta + dis + xdh (1 node per thread, coalesced)
    int cb = b * CAP;                    // bucket-strided overflow base
    int node = (b << 8) + t;
    if (node < n) {
        int deg = s_hist[t];
        meta[node] = ((unsigned int)deg << 21) | (unsigned int)(cb + s_start[t]);
        float di = rsqrtf((float)(deg + 1));   // +1 self-loop
        dis[node] = di;
        const float4* xi = (const float4*)(x + (size_t)node * IN_DIM);
        float4 a = xi[0], c = xi[1];
        union { __half2 h[4]; int iv[4]; } u;
        u.h[0] = __float22half2_rn(make_float2(a.x * di, a.y * di));
        u.h[1] = __float22half2_rn(make_float2(a.z * di, a.w * di));
        u.h[2] = __float22half2_rn(make_float2(c.x * di, c.y * di));
        u.h[3] = __float22half2_rn(make_float2(c.z * di, c.w * di));
        ((int4*)xdh)[node] = make_int4(u.iv[0], u.iv[1], u.iv[2], u.iv[3]);
    } else if (node == n) {
        ((int4*)xdh)[n] = make_int4(0, 0, 0, 0);           // dummy zero row
    }
    // place: first 16 per node into LDS pad; overflow -> bucket-strided csr_ovf (rare)
#pragma unroll
    for (int r = 0; r < 10; ++r) {
        if (rdl[r] == 0xFFFFFFFFu) continue;
        int dl = (int)(rdl[r] & 255u);
        int pos = (int)(rdl[r] >> 8);
        int sidx = (int)rsx[r];
        if (pos < SLOTS) s_pad[dl * SLOTS + pos] = sidx;
        else             csr_ovf[cb + s_start[dl] + pos] = sidx;
    }
    __syncthreads();
    // coalesced int4 flush (guard phantom nodes past n)
    for (int i = t; i < NPB * SLOTS / 4; i += 256) {
        int node2 = (b << 8) + (i >> 2);
        if (node2 < n)
            ((int4*)csr_pad)[(size_t)(b << 8) * 4 + i] = ((int4*)s_pad)[i];
    }
}

// ---------------- agg1 + MLP fused: node per LANE (R14 form) ----------------
// weights read from global with WAVE-UNIFORM addresses -> s_load/SGPR operands.
// Output channel-split: y2a[node]=ch0..7 (int4), y2b[node]=ch8..11 (int2).
__global__ void __launch_bounds__(256) k_agg1f(
        const int* __restrict__ csr_pad, const int* __restrict__ csr_ovf,
        const unsigned int* __restrict__ meta, const __half2* __restrict__ xdh,
        const float* __restrict__ dis, const float* __restrict__ W1,
        const float* __restrict__ b1, const float* __restrict__ W2,
        int4* __restrict__ y2a, int2* __restrict__ y2b, int n) {
    int node = blockIdx.x * 256 + threadIdx.x;
    if (node > n) return;
    if (node == n) {                     // dummy zero row for agg2
        y2a[n] = make_int4(0, 0, 0, 0);
        y2b[n] = make_int2(0, 0);
        return;
    }
    const int4* pr = (const int4*)(csr_pad + (size_t)node * SLOTS);
    int4 p0 = pr[0], p1 = pr[1], p2 = pr[2], p3 = pr[3];
    unsigned int m = meta[node];
    const int4* xt = (const int4*)xdh;

    float acc[8] = {0, 0, 0, 0, 0, 0, 0, 0};
    int idx[16] = {p0.x, p0.y, p0.z, p0.w, p1.x, p1.y, p1.z, p1.w,
                   p2.x, p2.y, p2.z, p2.w, p3.x, p3.y, p3.z, p3.w};
    acc_row8(acc, xt[node]);             // self-loop
#pragma unroll
    for (int i = 0; i < 16; ++i) acc_row8(acc, xt[(size_t)idx[i]]);
    int deg = m >> 21;
    if (deg > SLOTS) {                   // rare overflow
        int r0 = (int)(m & 0x1FFFFF);
        for (int r = SLOTS; r < deg; ++r) acc_row8(acc, xt[(size_t)csr_ovf[r0 + r]]);
    }
    float di = dis[node];
    float z[8];
#pragma unroll
    for (int k = 0; k < 8; ++k) z[k] = acc[k] * di;

    float y2[H2];
#pragma unroll
    for (int j = 0; j < H2; ++j) y2[j] = 0.f;
    for (int d = 0; d < H1; ++d) {       // d wave-uniform -> s_load weights
        float h = b1[d];
#pragma unroll
        for (int k = 0; k < 8; ++k) h = fmaf(z[k], W1[k * H1 + d], h);
        h = fmaxf(h, 0.f);
#pragma unroll
        for (int j = 0; j < H2; ++j) y2[j] = fmaf(h, W2[d * H2 + j], y2[j]);
    }
    union { __half2 h2v[6]; int iv[6]; } u;
#pragma unroll
    for (int q = 0; q < 6; ++q)
        u.h2v[q] = __float22half2_rn(make_float2(y2[2 * q] * di, y2[2 * q + 1] * di));
    y2a[node] = make_int4(u.iv[0], u.iv[1], u.iv[2], u.iv[3]);
    y2b[node] = make_int2(u.iv[4], u.iv[5]);
}

// ---------------- layer-2 aggregation pass A (ch 0-7) + fused max-pool ----------------
// gathers from y2a (3.2MB, fits 4MB per-XCD L2 -> L2-resident like agg1f's xdh)
__global__ void __launch_bounds__(256) k_agg2a(
        const int* __restrict__ csr_pad, const int* __restrict__ csr_ovf,
        const unsigned int* __restrict__ meta, const int4* __restrict__ y2a,
        const float* __restrict__ dis, const float* __restrict__ b2,
        const int* __restrict__ batch, unsigned int* __restrict__ pooled, int n) {
    int node = blockIdx.x * 256 + threadIdx.x;
    int lane = threadIdx.x & 63;
    bool active = node < n;
    float v[8] = {0, 0, 0, 0, 0, 0, 0, 0};
    int gid = 0x7fffffff;
    if (active) {
        const int4* pr = (const int4*)(csr_pad + (size_t)node * SLOTS);
        int4 p0 = pr[0], p1 = pr[1], p2 = pr[2], p3 = pr[3];
        unsigned int m = meta[node];
        float acc[8] = {0, 0, 0, 0, 0, 0, 0, 0};
        int idx[16] = {p0.x, p0.y, p0.z, p0.w, p1.x, p1.y, p1.z, p1.w,
                       p2.x, p2.y, p2.z, p2.w, p3.x, p3.y, p3.z, p3.w};
        acc_row8(acc, y2a[node]);            // self-loop
#pragma unroll
        for (int i = 0; i < 16; ++i) acc_row8(acc, y2a[(size_t)idx[i]]);
        int deg = m >> 21;
        if (deg > SLOTS) {                   // rare overflow
            int r0 = (int)(m & 0x1FFFFF);
            for (int r = SLOTS; r < deg; ++r) acc_row8(acc, y2a[(size_t)csr_ovf[r0 + r]]);
        }
        float di = dis[node];
#pragma unroll
        for (int q = 0; q < 8; ++q) v[q] = fmaxf(fmaf(acc[q], di, b2[q]), 0.f);
        gid = batch[node];
    }
    // wave segmented inclusive max-scan (batch sorted => segments contiguous)
#pragma unroll
    for (int off = 1; off < 64; off <<= 1) {
        int g2 = __shfl_up(gid, off, 64);
        bool merge = (lane >= off) && (g2 == gid);
#pragma unroll
        for (int q = 0; q < 8; ++q) {
            float tv = __shfl_up(v[q], off, 64);
            if (merge) v[q] = fmaxf(v[q], tv);
        }
    }
    int gnext = __shfl_down(gid, 1, 64);
    bool last = (lane == 63) || (gnext != gid);
    if (last && gid != 0x7fffffff) {
        unsigned int* pp = pooled + (size_t)gid * 12;
#pragma unroll
        for (int q = 0; q < 8; ++q) atomicMax(&pp[q], __float_as_uint(v[q]));
    }
}

// ---------------- layer-2 aggregation pass B (ch 8-11) + fused max-pool ----------------
// gathers from y2b (1.6MB, L2-resident)
__global__ void __launch_bounds__(256) k_agg2b(
        const int* __restrict__ csr_pad, const int* __restrict__ csr_ovf,
        const unsigned int* __restrict__ meta, const int2* __restrict__ y2b,
        const float* __restrict__ dis, const float* __restrict__ b2,
        const int* __restrict__ batch, unsigned int* __restrict__ pooled, int n) {
    int node = blockIdx.x * 256 + threadIdx.x;
    int lane = threadIdx.x & 63;
    bool active = node < n;
    float v[4] = {0, 0, 0, 0};
    int gid = 0x7fffffff;
    if (active) {
        const int4* pr = (const int4*)(csr_pad + (size_t)node * SLOTS);
        int4 p0 = pr[0], p1 = pr[1], p2 = pr[2], p3 = pr[3];
        unsigned int m = meta[node];
        float acc[4] = {0, 0, 0, 0};
        auto addrow4 = [&](int nb) {
            int2 rv = y2b[(size_t)nb];
            const __half2* h = (const __half2*)&rv;
#pragma unroll
            for (int q = 0; q < 2; ++q) {
                float2 f = __half22float2(h[q]);
                acc[2 * q] += f.x; acc[2 * q + 1] += f.y;
            }
        };
        int idx[16] = {p0.x, p0.y, p0.z, p0.w, p1.x, p1.y, p1.z, p1.w,
                       p2.x, p2.y, p2.z, p2.w, p3.x, p3.y, p3.z, p3.w};
        addrow4(node);                       // self-loop
#pragma unroll
        for (int i = 0; i < 16; ++i) addrow4(idx[i]);
        int deg = m >> 21;
        if (deg > SLOTS) {                   // rare overflow
            int r0 = (int)(m & 0x1FFFFF);
            for (int r = SLOTS; r < deg; ++r) addrow4(csr_ovf[r0 + r]);
        }
        float di = dis[node];
#pragma unroll
        for (int q = 0; q < 4; ++q) v[q] = fmaxf(fmaf(acc[q], di, b2[8 + q]), 0.f);
        gid = batch[node];
    }
    // wave segmented inclusive max-scan
#pragma unroll
    for (int off = 1; off < 64; off <<= 1) {
        int g2 = __shfl_up(gid, off, 64);
        bool merge = (lane >= off) && (g2 == gid);
#pragma unroll
        for (int q = 0; q < 4; ++q) {
            float tv = __shfl_up(v[q], off, 64);
            if (merge) v[q] = fmaxf(v[q], tv);
        }
    }
    int gnext = __shfl_down(gid, 1, 64);
    bool last = (lane == 63) || (gnext != gid);
    if (last && gid != 0x7fffffff) {
        unsigned int* pp = pooled + (size_t)gid * 12 + 8;
#pragma unroll
        for (int q = 0; q < 4; ++q) atomicMax(&pp[q], __float_as_uint(v[q]));
    }
}

// ---------------- head: logits + log_softmax from pooled ----------------
__global__ void k_head(const unsigned int* __restrict__ pooled,
                       const float* __restrict__ Wl, const float* __restrict__ bl,
                       float* __restrict__ out, int g) {
    int i = blockIdx.x * 256 + threadIdx.x;
    if (i >= g) return;
    float l0 = bl[0], l1 = bl[1];
#pragma unroll
    for (int k = 0; k < H2; ++k) {
        float pv = __uint_as_float(pooled[(size_t)i * 12 + k]);
        l0 = fmaf(pv, Wl[k * 2 + 0], l0);
        l1 = fmaf(pv, Wl[k * 2 + 1], l1);
    }
    float m = fmaxf(l0, l1);
    float lse = m + logf(expf(l0 - m) + expf(l1 - m));
    out[i * 2 + 0] = l0 - lse;
    out[i * 2 + 1] = l1 - lse;
}

extern "C" void kernel_launch(void* const* d_in, const int* in_sizes, int n_in,
                              void* d_out, int out_size, void* d_ws, size_t ws_size,
                              hipStream_t stream) {
    const float* x   = (const float*)d_in[0];
    const int* ei    = (const int*)d_in[1];
    const int* batch = (const int*)d_in[2];
    const float* W1  = (const float*)d_in[3];
    const float* b1  = (const float*)d_in[4];
    const float* W2  = (const float*)d_in[5];
    const float* b2  = (const float*)d_in[6];
    const float* Wl  = (const float*)d_in[7];
    const float* bl  = (const float*)d_in[8];
    float* out = (float*)d_out;

    const int N = in_sizes[0] / IN_DIM;   // 200000
    const int E = in_sizes[1] / 2;        // 1600000
    const int G = out_size / 2;           // 2000
    const int* src = ei;
    const int* dst = ei + E;

    auto cdiv = [](long long a, int b) { return (int)((a + b - 1) / b); };

    // workspace carve, 64B-aligned (bcursor+pooled first: single zeroing memset)
    char* wp = (char*)d_ws;
    auto carve = [&](size_t bytes) {
        char* p = wp;
        wp += (bytes + 63) & ~(size_t)63;
        return p;
    };
    int*          bcursor = (int*)carve(NBK * 4);
    unsigned int* pooled  = (unsigned int*)carve((size_t)G * H2 * 4);
    unsigned int* meta    = (unsigned int*)carve((size_t)N * 4);
    float*        dis     = (float*)carve((size_t)N * 4);
    __half2*      xdh     = (__half2*)carve((size_t)(N + 1) * 16);   // 16B rows
    int4*         y2a     = (int4*)carve((size_t)(N + 1) * 16);      // ch0-7, 3.2MB
    int2*         y2b     = (int2*)carve((size_t)(N + 1) * 8);       // ch8-11, 1.6MB
    uint32_t*     pairs   = (uint32_t*)carve((size_t)NBK * CAP * 4);
    int*          csr_pad = (int*)carve((size_t)N * SLOTS * 4);
    int*          csr_ovf = (int*)carve((size_t)NBK * CAP * 4);

    size_t zspan = (char*)(pooled + (size_t)G * H2) - (char*)bcursor;
    (void)hipMemsetAsync(bcursor, 0, zspan, stream);

    // CSR build (bucket-sorted binA -> padded csr in binB, fused meta/dis/xdh)
    k_binA<<<cdiv(E, CHUNK), 256, 0, stream>>>(src, dst, pairs, bcursor, E);
    k_binB<<<NBK, 256, 0, stream>>>(pairs, bcursor, x, csr_pad, csr_ovf,
                                    meta, dis, xdh, N);

    // fused layer-1 agg + MLP; channel-split layer-2 agg passes; head
    k_agg1f<<<cdiv((long long)N + 1, 256), 256, 0, stream>>>(
        csr_pad, csr_ovf, meta, xdh, dis, W1, b1, W2, y2a, y2b, N);
    k_agg2a<<<cdiv(N, 256), 256, 0, stream>>>(csr_pad, csr_ovf, meta, y2a,
                                              dis, b2, batch, pooled, N);
    k_agg2b<<<cdiv(N, 256), 256, 0, stream>>>(csr_pad, csr_ovf, meta, y2b,
                                              dis, b2, batch, pooled, N);
    k_head<<<cdiv(G, 256), 256, 0, stream>>>(pooled, Wl, bl, out, G);
}